// Round 5
// baseline (35842.413 us; speedup 1.0000x reference)
//
#include <hip/hip_runtime.h>
#include <math.h>

#define TT 2048
#define DIN 64
#define HH 256
#define BR 32

typedef __attribute__((ext_vector_type(8))) short bf16x8;
typedef __attribute__((ext_vector_type(16))) float f32x16;
typedef unsigned short u16;

// ---- LDS layout: shorts region, then floats region ----
#define XS_STR 72    // x stage row stride (64 + 8 pad)
#define HS_STR 264   // h stage row stride (256 + 8 pad)
#define GB_STR 36    // gate buffer row stride (32 + 4 pad)

#define OFF_XS    0                    // [2 parity][hi/lo][32][72] = 9216 shorts
#define OFF_HS0   9216                 // [hi/lo][32][264] = 16896
#define OFF_HS1   26112                // 16896
#define OFF_W0LO  43008                // 20 tiles * 64 lanes * 8 = 10240
#define OFF_W1LO  53248                // 32 tiles * 64 lanes * 8 = 16384
#define SH_SHORTS 69632
#define SH_BYTES  (SH_SHORTS*2)        // 139264 B
#define LDS_BYTES (SH_BYTES + 2368*4)  // + gb0,gb1,biases = 148736 B

__device__ __forceinline__ u16 f2bf(float f){
    unsigned u = __builtin_bit_cast(unsigned, f);
    u += 0x7fffu + ((u >> 16) & 1u);   // RNE to bf16
    return (u16)(u >> 16);
}
__device__ __forceinline__ float bf2f(u16 h){
    unsigned u = ((unsigned)h) << 16;
    return __builtin_bit_cast(float, u);
}
__device__ __forceinline__ float sigf(float v){ return 1.0f/(1.0f+__expf(-v)); }

__device__ __forceinline__ void split8(float4 a, float4 b, bf16x8& hi, bf16x8& lo){
    float v[8] = {a.x,a.y,a.z,a.w,b.x,b.y,b.z,b.w};
    #pragma unroll
    for (int j=0;j<8;++j){
        u16 h = f2bf(v[j]);
        hi[j] = (short)h;
        lo[j] = (short)f2bf(v[j] - bf2f(h));
    }
}

// flag-array group barrier: one 128B-spaced slot per WG, release store + 32-lane acquire poll
__device__ __forceinline__ void group_barrier(unsigned* flg, int ug, unsigned epoch){
    __syncthreads();   // all waves drain vmcnt -> publishes at L2
    if (threadIdx.x == 0)
        __hip_atomic_store(flg + ug*32, epoch, __ATOMIC_RELEASE, __HIP_MEMORY_SCOPE_AGENT);
    if (threadIdx.x < 32) {
        while (__hip_atomic_load(flg + threadIdx.x*32, __ATOMIC_ACQUIRE, __HIP_MEMORY_SCOPE_AGENT) < epoch)
            __builtin_amdgcn_s_sleep(1);
    }
    __syncthreads();
}

template<int N>
__device__ __forceinline__ void load_wh0(bf16x8* wh, int t0, int G, int hk8,
                                         const float* Wih0, const float* Whh0){
    #pragma unroll
    for (int i=0;i<N;++i){
        int k = (t0+i)*16 + hk8;
        const float* p = (k < 64) ? (Wih0 + (size_t)G*64 + k) : (Whh0 + (size_t)G*HH + (k-64));
        bf16x8 hi_, lo_; split8(*(const float4*)p, *(const float4*)(p+4), hi_, lo_);
        wh[i] = hi_;
    }
}
template<int N>
__device__ __forceinline__ void load_wh1(bf16x8* wh, int t0, int G, int hk8,
                                         const float* Wih1, const float* Whh1){
    #pragma unroll
    for (int i=0;i<N;++i){
        int k = (t0+i)*16 + hk8;
        const float* p = (k < 256) ? (Wih1 + (size_t)G*HH + k) : (Whh1 + (size_t)G*HH + (k-256));
        bf16x8 hi_, lo_; split8(*(const float4*)p, *(const float4*)(p+4), hi_, lo_);
        wh[i] = hi_;
    }
}

template<int N>
__device__ __forceinline__ void mm_run(const short* aHi, const short* aLo, const short* wlo,
                                       const bf16x8* wh, f32x16* ac){
    #pragma unroll
    for (int i=0;i<N;++i){
        bf16x8 ah = *(const bf16x8*)(aHi + i*16);
        bf16x8 al = *(const bf16x8*)(aLo + i*16);
        bf16x8 wl = *(const bf16x8*)(wlo + i*512);
        ac[i&1] = __builtin_amdgcn_mfma_f32_32x32x16_bf16(ah, wh[i], ac[i&1], 0,0,0);
        ac[i&1] = __builtin_amdgcn_mfma_f32_32x32x16_bf16(al, wh[i], ac[i&1], 0,0,0);
        ac[i&1] = __builtin_amdgcn_mfma_f32_32x32x16_bf16(ah, wl,    ac[i&1], 0,0,0);
    }
}

__global__ __launch_bounds__(512, 1)
void lstm_mfma32(const float* __restrict__ x,
                 const float* __restrict__ Wih0, const float* __restrict__ Whh0,
                 const float* __restrict__ bih0, const float* __restrict__ bhh0,
                 const float* __restrict__ Wih1, const float* __restrict__ Whh1,
                 const float* __restrict__ bih1, const float* __restrict__ bhh1,
                 const float* __restrict__ Wd,   const float* __restrict__ bd,
                 float* __restrict__ out, u16* __restrict__ hb,
                 unsigned* __restrict__ flags)
{
    extern __shared__ char smem[];
    short* sh = (short*)smem;
    float* sf  = (float*)(smem + SH_BYTES);
    float* gb0 = sf;             // [32][36]
    float* gb1 = sf + 1152;      // [32][36]
    float* b0s = sf + 2304;      // [32]
    float* b1s = sf + 2336;      // [32]

    const int tid = threadIdx.x;
    const int w   = blockIdx.x;
    const int rb  = w & 7;      // row-group (XCD affinity)
    const int ug  = w >> 3;     // unit-group 0..31
    const int rbase = rb * BR;
    const int u0  = ug * 8;
    unsigned* flg = flags + rb * 1024;

    // h planes in ws (u16): h0hi, h0lo, h1hi, h1lo each [2 parity][65536]
    // plane p base = p*131072 + parity*65536

    const int l   = tid & 63;
    const int wid = tid >> 6;
    const int col = l & 31;          // MFMA col (B/D) and row (A)
    const int kg  = l >> 5;          // k-group
    const int hk8 = kg * 8;
    const int row = col;

    // per-wave role: layer + k-tile range (52 tiles total, 3 MFMA each)
    // wid0: L0 t0..6 (x-tiles 0-3 + h0 4-6); wid1: L0 7-13; wid2: L0 14-19
    // wid3: L1 0-7; wid4: L1 8-15; wid5: L1 16-23; wid6: L1 24-31; wid7: helper
    const int G = (col>>3)*HH + u0 + (col&7);

    bf16x8 wh[8];
    if      (wid==0) load_wh0<7>(wh, 0,  G, hk8, Wih0, Whh0);
    else if (wid==1) load_wh0<7>(wh, 7,  G, hk8, Wih0, Whh0);
    else if (wid==2) load_wh0<6>(wh, 14, G, hk8, Wih0, Whh0);
    else if (wid==3) load_wh1<8>(wh, 0,  G, hk8, Wih1, Whh1);
    else if (wid==4) load_wh1<8>(wh, 8,  G, hk8, Wih1, Whh1);
    else if (wid==5) load_wh1<8>(wh, 16, G, hk8, Wih1, Whh1);
    else if (wid==6) load_wh1<8>(wh, 24, G, hk8, Wih1, Whh1);

    // W-lo fragments -> LDS, [tile][lane][8] lane-linear
    for (int f = tid; f < 20*64; f += 512){
        int kt = f >> 6, ll = f & 63;
        int c2 = ll & 31;
        int G2 = (c2>>3)*HH + u0 + (c2&7);
        int k  = kt*16 + (ll>>5)*8;
        const float* p = (k<64) ? (Wih0 + (size_t)G2*64 + k) : (Whh0 + (size_t)G2*HH + (k-64));
        bf16x8 hi_, lo_; split8(*(const float4*)p, *(const float4*)(p+4), hi_, lo_);
        *(bf16x8*)(sh + OFF_W0LO + f*8) = lo_;
    }
    for (int f = tid; f < 32*64; f += 512){
        int kt = f >> 6, ll = f & 63;
        int c2 = ll & 31;
        int G2 = (c2>>3)*HH + u0 + (c2&7);
        int k  = kt*16 + (ll>>5)*8;
        const float* p = (k<256) ? (Wih1 + (size_t)G2*HH + k) : (Whh1 + (size_t)G2*HH + (k-256));
        bf16x8 hi_, lo_; split8(*(const float4*)p, *(const float4*)(p+4), hi_, lo_);
        *(bf16x8*)(sh + OFF_W1LO + f*8) = lo_;
    }

    if (tid < 32){
        int gg_ = (tid>>3)*HH + u0 + (tid&7);
        b0s[tid] = bih0[gg_] + bhh0[gg_];
        b1s[tid] = bih1[gg_] + bhh1[gg_];
    }
    if (tid < 256){
        // zero my h slots, all planes/parities (ws poisoned)
        int zr = tid>>3, zu = tid&7;
        size_t off = (size_t)(rbase+zr)*HH + u0 + zu;
        hb[off]=0; hb[65536+off]=0; hb[131072+off]=0; hb[196608+off]=0;
        hb[262144+off]=0; hb[327680+off]=0; hb[393216+off]=0; hb[458752+off]=0;
    } else {
        // stage x(0) into xs parity 0
        int lo_ = tid-256;
        int xr = lo_>>3, xk = (lo_&7)*8;
        const float* xp = x + (size_t)(rbase+xr)*(TT*DIN) + xk;
        bf16x8 xh, xl; split8(*(const float4*)xp, *(const float4*)(xp+4), xh, xl);
        *(bf16x8*)(sh + OFF_XS + xr*XS_STR + xk) = xh;
        *(bf16x8*)(sh + OFF_XS + 2304 + xr*XS_STR + xk) = xl;
    }
    group_barrier(flg, ug, 1u);

    // A-frag lane base pointers (row = l&31, k-run = (l>>5)*8)
    const short* a0h = sh + OFF_HS0 +        row*HS_STR + hk8;
    const short* a0l = sh + OFF_HS0 + 8448 + row*HS_STR + hk8;
    const short* a1h = sh + OFF_HS1 +        row*HS_STR + hk8;
    const short* a1l = sh + OFF_HS1 + 8448 + row*HS_STR + hk8;
    const short* wlo0 = sh + OFF_W0LO + l*8;   // step 512 shorts per tile
    const short* wlo1 = sh + OFF_W1LO + l*8;

    // cell-update mapping
    const int upd = (tid < 256) ? tid : (tid - 256);
    const int ur = upd >> 3, uu = upd & 7;
    const size_t poff = (size_t)(rbase+ur)*HH + u0 + uu;

    float c0s = 0.f, c1s = 0.f;

    for (int k = 0; k <= TT; ++k){
        // ---- stage h0(k-1), h1(k-2) (parity rd) + zero gate buffers ----
        {
            const unsigned rdo = ((k+1)&1) * 65536u;
            #pragma unroll
            for (int j=0;j<8;++j){
                int cid = tid + j*512;
                int p = cid >> 10, u = cid & 1023;
                int hr = u >> 5, hk = (u&31)*8;
                *(uint4*)(sh + OFF_HS0 + p*8448 + hr*HS_STR + hk) =
                    *(const uint4*)(hb + (size_t)p*131072 + rdo + (size_t)(rbase+hr)*HH + hk);
            }
            float4 z = {0.f,0.f,0.f,0.f};
            for (int i4 = tid; i4 < 576; i4 += 512) *(float4*)(sf + i4*4) = z;
        }
        __syncthreads();

        // ---- MFMA phase: 7 waves, partial sums merged via LDS f32 atomics ----
        if (wid < 3){
            if (k < TT){
                f32x16 ac[2] = {};
                if (wid==0){
                    const short* xh = sh + OFF_XS + (k&1)*4608 +        row*XS_STR + hk8;
                    const short* xl = sh + OFF_XS + (k&1)*4608 + 2304 + row*XS_STR + hk8;
                    mm_run<4>(xh, xl, wlo0, wh, ac);
                    mm_run<3>(a0h, a0l, wlo0 + 4*512, wh+4, ac);
                } else if (wid==1){
                    mm_run<7>(a0h + 3*16, a0l + 3*16, wlo0 + 7*512, wh, ac);
                } else {
                    mm_run<6>(a0h + 10*16, a0l + 10*16, wlo0 + 14*512, wh, ac);
                }
                f32x16 aa = ac[0] + ac[1];
                float* gp = gb0 + col;
                #pragma unroll
                for (int r2=0;r2<16;++r2){
                    int rr = (r2&3) + ((r2>>2)<<3) + (kg<<2);
                    atomicAdd(gp + rr*GB_STR, aa[r2]);
                }
            }
        } else if (wid < 7){
            if (k >= 1){
                f32x16 ac[2] = {};
                if      (wid==3) mm_run<8>(a0h,          a0l,          wlo1,          wh, ac);
                else if (wid==4) mm_run<8>(a0h + 8*16,   a0l + 8*16,   wlo1 + 8*512,  wh, ac);
                else if (wid==5) mm_run<8>(a1h,          a1l,          wlo1 + 16*512, wh, ac);
                else             mm_run<8>(a1h + 8*16,   a1l + 8*16,   wlo1 + 24*512, wh, ac);
                f32x16 aa = ac[0] + ac[1];
                float* gp = gb1 + col;
                #pragma unroll
                for (int r2=0;r2<16;++r2){
                    int rr = (r2&3) + ((r2>>2)<<3) + (kg<<2);
                    atomicAdd(gp + rr*GB_STR, aa[r2]);
                }
            }
        }
        __syncthreads();

        // ---- cell updates + publish + x prefetch ----
        const unsigned wro = (k&1) * 65536u;
        if (tid < 256){
            if (k < TT){
                float gi = gb0[ur*GB_STR + uu]      + b0s[uu];
                float gf = gb0[ur*GB_STR + 8 + uu]  + b0s[8+uu];
                float gg = gb0[ur*GB_STR + 16 + uu] + b0s[16+uu];
                float go = gb0[ur*GB_STR + 24 + uu] + b0s[24+uu];
                c0s = sigf(gf)*c0s + sigf(gi)*tanhf(gg);
                float hn = sigf(go)*tanhf(c0s);
                u16 hhv = f2bf(hn), hlv = f2bf(hn - bf2f(hhv));
                hb[wro + poff]          = hhv;
                hb[131072 + wro + poff] = hlv;
            }
        } else {
            if (k >= 1){
                float gi = gb1[ur*GB_STR + uu]      + b1s[uu];
                float gf = gb1[ur*GB_STR + 8 + uu]  + b1s[8+uu];
                float gg = gb1[ur*GB_STR + 16 + uu] + b1s[16+uu];
                float go = gb1[ur*GB_STR + 24 + uu] + b1s[24+uu];
                c1s = sigf(gf)*c1s + sigf(gi)*tanhf(gg);
                float hn = sigf(go)*tanhf(c1s);
                u16 hhv = f2bf(hn), hlv = f2bf(hn - bf2f(hhv));
                hb[262144 + wro + poff] = hhv;
                hb[393216 + wro + poff] = hlv;
            }
            if (k + 1 < TT){
                int lo_ = tid-256;
                int xr = lo_>>3, xk = (lo_&7)*8;
                const float* xp = x + (size_t)(rbase+xr)*(TT*DIN) + (size_t)(k+1)*DIN + xk;
                bf16x8 xh, xl; split8(*(const float4*)xp, *(const float4*)(xp+4), xh, xl);
                int pb = ((k+1)&1)*4608;
                *(bf16x8*)(sh + OFF_XS + pb +        xr*XS_STR + xk) = xh;
                *(bf16x8*)(sh + OFF_XS + pb + 2304 + xr*XS_STR + xk) = xl;
            }
        }
        group_barrier(flg, ug, (unsigned)(k+2));
    }

    // ---- dense head: out = h1(T-1) @ Wd^T + bd ; h1(T-1) in parity-0 planes ----
    if (ug == 0 && tid < 64){
        int r = tid >> 1, j = tid & 1;
        const u16* hhp = hb + 262144 + (size_t)(rbase+r)*HH;
        const u16* hlp = hb + 393216 + (size_t)(rbase+r)*HH;
        const float* wdp = Wd + j*HH;
        float a = bd[j];
        #pragma unroll 4
        for (int q = 0; q < HH; ++q)
            a += (bf2f(hhp[q]) + bf2f(hlp[q])) * wdp[q];
        out[(rbase+r)*2 + j] = a;
    }
}

extern "C" void kernel_launch(void* const* d_in, const int* in_sizes, int n_in,
                              void* d_out, int out_size, void* d_ws, size_t ws_size,
                              hipStream_t stream) {
    const float* x    = (const float*)d_in[0];
    const float* Wih0 = (const float*)d_in[1];
    const float* Whh0 = (const float*)d_in[2];
    const float* bih0 = (const float*)d_in[3];
    const float* bhh0 = (const float*)d_in[4];
    const float* Wih1 = (const float*)d_in[5];
    const float* Whh1 = (const float*)d_in[6];
    const float* bih1 = (const float*)d_in[7];
    const float* bhh1 = (const float*)d_in[8];
    const float* Wd   = (const float*)d_in[9];
    const float* bd   = (const float*)d_in[10];
    float* out = (float*)d_out;

    unsigned* flags = (unsigned*)d_ws;            // 32 KB flag slots (8 groups x 32 WGs x 128B)
    u16* hb = (u16*)((char*)d_ws + 32768);        // 1 MB h hi/lo planes

    hipMemsetAsync(d_ws, 0, 32768, stream);

    hipFuncSetAttribute((const void*)lstm_mfma32,
                        hipFuncAttributeMaxDynamicSharedMemorySize, LDS_BYTES);

    lstm_mfma32<<<dim3(256), dim3(512), LDS_BYTES, stream>>>(
        x, Wih0, Whh0, bih0, bhh0, Wih1, Whh1, bih1, bhh1,
        Wd, bd, out, hb, flags);
}